// Round 9
// baseline (297.534 us; speedup 1.0000x reference)
//
#include <hip/hip_runtime.h>
#include <hip/hip_cooperative_groups.h>
#include <stdint.h>

namespace cg = cooperative_groups;

typedef unsigned short u16;
typedef __attribute__((ext_vector_type(8))) short short8;
typedef __attribute__((ext_vector_type(4))) float floatx4;

#define NB 32
#define NC 256
#define NH 32
#define NW 32
#define NO 256
#define NPIX (NH*NW)     // 1024
#define KPIX 9
#define NG 9             // subarrays (groups)
#define RUN 32           // padded run length (per kernel-tap within group)
#define GK (NG*RUN)      // 288 k-slots per group
#define KTOT (NG*GK)     // 2592 k-slots
#define PADH 34
#define PADSP (PADH*PADH)       // 1156
#define QA_BSTRIDE (PADSP*NC)   // 295936 elems per batch

#define AS1 __attribute__((address_space(1)))
#define AS3 __attribute__((address_space(3)))

// helper: reduce the 1024 x-slots and 64 w-slots from pmax
__device__ inline void reduce_pmax(const float* pmax, int tid, int nthreads,
                                   float* sred, float& mx_out, float& mw_out) {
  const float4* pf4 = (const float4*)pmax;
  float mx = 0.f, mw = 0.f;
  for (int t = tid; t < 256; t += nthreads) {
    float4 v = pf4[t];
    mx = fmaxf(mx, fmaxf(fmaxf(v.x, v.y), fmaxf(v.z, v.w)));
  }
  if (tid < 16) {
    float4 v = pf4[256 + tid];
    mw = fmaxf(fmaxf(v.x, v.y), fmaxf(v.z, v.w));
  }
#pragma unroll
  for (int off = 32; off > 0; off >>= 1) {
    mx = fmaxf(mx, __shfl_down(mx, off, 64));
    mw = fmaxf(mw, __shfl_down(mw, off, 64));
  }
  int lane = tid & 63, wv = tid >> 6, nw = nthreads >> 6;
  if (lane == 0) { sred[wv] = mx; sred[8 + wv] = mw; }
  __syncthreads();
  mx = sred[0]; mw = sred[8];
  for (int i = 1; i < nw; i++) { mx = fmaxf(mx, sred[i]); mw = fmaxf(mw, sred[8 + i]); }
  mx_out = mx; mw_out = mw;
}

// ---------------- cooperative prep: absmax + borders | grid.sync | quantize ----------------
// Phase A (1024 blocks): per-block x-absmax -> pmax[bid]; blocks<64 also w-absmax ->
// pmax[1024+bid]; blocks 64..351 zero one border unit each. Phase B: grid-stride over
// 8192 act tiles + 2592 weight chunks (f64 math EXACTLY as all passing rounds).
__global__ __launch_bounds__(256, 4) void coop_prep(const float* __restrict__ x,
                                                    const float* __restrict__ w,
                                                    float* __restrict__ pmax,
                                                    u16* __restrict__ qa,
                                                    u16* __restrict__ wq,
                                                    float* __restrict__ lossp) {
  __shared__ float sm[4];
  __shared__ float sred[16];
  __shared__ u16 t[32][33];
  const int bid = blockIdx.x, tid = threadIdx.x;
  const int lane = tid & 63, wv4 = tid >> 6;

  // ---- phase A: x absmax (all 1024 blocks) ----
  {
    const float4* x4 = (const float4*)x;
    const int nx4 = (NB * NC * NH * NW) / 4;
    float m = 0.f;
    for (int i = bid * 256 + tid; i < nx4; i += 1024 * 256) {
      float4 v = x4[i];
      m = fmaxf(m, fmaxf(fmaxf(fabsf(v.x), fabsf(v.y)), fmaxf(fabsf(v.z), fabsf(v.w))));
    }
#pragma unroll
    for (int off = 32; off > 0; off >>= 1)
      m = fmaxf(m, __shfl_down(m, off, 64));
    if (lane == 0) sm[wv4] = m;
    __syncthreads();
    if (tid == 0)
      pmax[bid] = fmaxf(fmaxf(sm[0], sm[1]), fmaxf(sm[2], sm[3]));
    __syncthreads();
  }
  if (bid < 64) {
    // ---- w absmax (64 blocks) ----
    const float4* w4 = (const float4*)w;
    const int nw4 = (NO * NC * KPIX) / 4;
    float m = 0.f;
    for (int i = bid * 256 + tid; i < nw4; i += 64 * 256) {
      float4 v = w4[i];
      m = fmaxf(m, fmaxf(fmaxf(fabsf(v.x), fabsf(v.y)), fmaxf(fabsf(v.z), fabsf(v.w))));
    }
#pragma unroll
    for (int off = 32; off > 0; off >>= 1)
      m = fmaxf(m, __shfl_down(m, off, 64));
    if (lane == 0) sm[wv4] = m;
    __syncthreads();
    if (tid == 0)
      pmax[1024 + bid] = fmaxf(fmaxf(sm[0], sm[1]), fmaxf(sm[2], sm[3]));
  } else if (bid < 352) {
    // ---- zero halo borders: 288 units (9 per batch) ----
    int zb = bid - 64;
    int b = zb / 9;
    int rem = (zb % 9) * 256 + tid;     // need <2112 (132 px * 16 ch-groups)
    if (rem < 2112) {
      int pb = rem >> 4, c16 = rem & 15;
      int y, xx;
      if (pb < 68) { y = (pb >= 34) ? 33 : 0; xx = pb % 34; }
      else { int q = pb - 68; y = 1 + (q >> 1); xx = (q & 1) ? 33 : 0; }
      uint4 z; z.x = z.y = z.z = z.w = 0u;
      *(uint4*)(qa + ((size_t)(b * PADH + y) * PADH + xx) * NC + c16 * 16) = z;
    }
  }

  cg::this_grid().sync();

  // ---- phase B: quantize (x now L3-resident) ----
  float mx, mw;
  reduce_pmax(pmax, tid, 256, sred, mx, mw);
  double sinvx = 255.0 / ((double)mx + 1e-12);
  double sinvw = 15.0 / ((double)mw + 1e-12);

#pragma unroll 1
  for (int u = bid; u < 8192 + 2592; u += 1024) {
    if (u < 8192) {
      int tx = tid & 31, ty = tid >> 5;
      int ct = u & 7, y = (u >> 3) & 31, b = u >> 8;
      __syncthreads();
#pragma unroll
      for (int j = 0; j < 4; j++) {
        int cl = ty + j * 8;
        float v = x[(((size_t)b * NC + ct * 32 + cl) * NH + y) * NW + tx];
        double q = rint((double)v * sinvx);
        float qf = (float)q;                       // integer, |q|<=255: exact in bf16
        t[cl][tx] = (u16)(__float_as_uint(qf) >> 16);
      }
      __syncthreads();
#pragma unroll
      for (int j = 0; j < 4; j++) {
        int xq = ty + j * 8;
        qa[((size_t)(b * PADH + y + 1) * PADH + (xq + 1)) * NC + ct * 32 + tx] = t[tx][xq];
      }
    } else {
      int idx = (u - 8192) * 256 + tid;            // < NO*KTOT = 663552 exactly
      if (idx == 0) *lossp = 0.0f;                 // a_loss output
      int o = idx / KTOT, kk = idx % KTOT;
      int g = kk / GK, rem = kk % GK;
      int r = rem / RUN, j = rem % RUN;
      int clo = (256 * g - r + 8) / 9;
      int chi = (256 * (g + 1) - r + 8) / 9; if (chi > NC) chi = NC;
      int cst = clo & ~3;
      int c = cst + j;
      float val = 0.f;
      if (c >= clo && c < chi) {
        float wvv = w[((size_t)o * NC + c) * KPIX + r];
        val = (float)rint((double)wvv * sinvw);
      }
      wq[idx] = (u16)(__float_as_uint(val) >> 16);
    }
  }
}

// ---------------- fused GEMM + per-group ADC (R6-proven 83us config) ----------------
// 128x64 block tile, 128 threads (2 waves x 64x64), grid (256,4)=1024 blocks = 4/CU.
// 96-K (3-run) chunks staged direct-to-LDS (16B async), source-side bank swizzle.
__global__ __launch_bounds__(128, 2) void gemm_adc(const u16* __restrict__ qa,
                                                   const u16* __restrict__ wq,
                                                   const float* __restrict__ pmax,
                                                   float* __restrict__ out) {
  __shared__ u16 lA[3 * 128 * RUN];   // 24 KB
  __shared__ u16 lB[3 * 64 * RUN];    // 12 KB
  __shared__ float sred[16];
  const int tid = threadIdx.x;
  float mx, mw;
  reduce_pmax(pmax, tid, 128, sred, mx, mw);

  const int mblk = blockIdx.x, nblk = blockIdx.y;
  const int b = mblk >> 3;
  const int p0 = (mblk & 7) * 128;        // pixel base (4 image rows of 32)
  const int n0 = nblk * 64;
  const int lane = tid & 63, w = tid >> 6;
  const int fm = lane & 15, fq = lane >> 4;
  const int swz = (fq + ((fm >> 1) & 3)) & 3;

  double sa = (double)mx + 1e-12;
  double sw = (double)mw + 1e-12;
  double Sstep = sa * sw * 0.999 / 459.0;   // I/step = intsum * Sstep

  // staging constants: slot s = tid + ii*128; row = (tid>>2)+ii*32; j' = tid&3
  // global k-word jsrc = ((tid&3) - ((tid>>3)&3)) & 3  (source-side bank swizzle)
  const int r0 = tid >> 2;
  const int jsrc = ((tid & 3) - ((tid >> 3) & 3)) & 3;
  const u16* Abase = qa + (size_t)b * QA_BSTRIDE
                     + (((p0 >> 5) + 1) * PADH + (r0 + 1)) * NC + jsrc * 8;
  const u16* Bbase = wq + (size_t)(n0 + r0) * KTOT + jsrc * 8;
  u16* Adst = &lA[tid * 8];
  u16* Bdst = &lB[tid * 8];

  floatx4 acc[4][4];
  float tot[4][4][4];
#pragma unroll
  for (int mi = 0; mi < 4; mi++)
#pragma unroll
    for (int ni = 0; ni < 4; ni++)
#pragma unroll
      for (int rr = 0; rr < 4; rr++) { acc[mi][ni][rr] = 0.f; tot[mi][ni][rr] = 0.f; }

#pragma unroll 1
  for (int g = 0; g < NG; g++) {
#pragma unroll 1
    for (int rc = 0; rc < 3; rc++) {
      int offA[3], kb[3];
#pragma unroll
      for (int ri = 0; ri < 3; ri++) {
        int r = rc * 3 + ri;
        int cst = ((256 * g - r + 8) / 9) & ~3;
        offA[ri] = ((rc - 1) * PADH + (ri - 1)) * NC + cst;  // (dy*34+dx)*256 + cst
        kb[ri] = g * GK + r * RUN;
      }
      // A: 12 async 16B loads (3 runs x 4 row-quarters)
#pragma unroll
      for (int ri = 0; ri < 3; ri++)
#pragma unroll
        for (int ii = 0; ii < 4; ii++)
          __builtin_amdgcn_global_load_lds(
              (const AS1 void*)(Abase + offA[ri] + ii * (PADH * NC)),
              (AS3 void*)(Adst + ri * 4096 + ii * 1024), 16, 0, 0);
      // B: 6 async 16B loads (3 runs x 2 row-halves)
#pragma unroll
      for (int ii = 0; ii < 6; ii++)
        __builtin_amdgcn_global_load_lds(
            (const AS1 void*)(Bbase + (ii & 1) * 32 * KTOT + kb[ii >> 1]),
            (AS3 void*)(Bdst + ii * 1024), 16, 0, 0);
      __syncthreads();
      // ---- 3 runs x 16 MFMA per wave ----
#pragma unroll
      for (int ri = 0; ri < 3; ri++) {
        short8 afr[4], bfr[4];
#pragma unroll
        for (int mi = 0; mi < 4; mi++)
          afr[mi] = *(const short8*)&lA[ri * 4096 + (w * 64 + mi * 16 + fm) * RUN + swz * 8];
#pragma unroll
        for (int ni = 0; ni < 4; ni++)
          bfr[ni] = *(const short8*)&lB[ri * 2048 + (ni * 16 + fm) * RUN + swz * 8];
#pragma unroll
        for (int mi = 0; mi < 4; mi++)
#pragma unroll
          for (int ni = 0; ni < 4; ni++)
            acc[mi][ni] = __builtin_amdgcn_mfma_f32_16x16x32_bf16(afr[mi], bfr[ni], acc[mi][ni], 0, 0, 0);
      }
      __syncthreads();
    }
    // ---- per-group ADC fold (f64 mul+rint EXACTLY as the passing kernels) ----
#pragma unroll
    for (int mi = 0; mi < 4; mi++)
#pragma unroll
      for (int ni = 0; ni < 4; ni++)
#pragma unroll
        for (int rr = 0; rr < 4; rr++) {
          double d = (double)acc[mi][ni][rr] * Sstep;
          float tf = (float)rint(d);
          tf = fminf(fmaxf(tf, -128.f), 127.f);
          tot[mi][ni][rr] += tf;
          acc[mi][ni][rr] = 0.f;
        }
  }
  // ---- epilogue ----
#pragma unroll
  for (int mi = 0; mi < 4; mi++)
#pragma unroll
    for (int ni = 0; ni < 4; ni++) {
      int o = n0 + ni * 16 + fm;
      int p = p0 + w * 64 + mi * 16 + fq * 4;
      float4 o4;
      o4.x = tot[mi][ni][0] * 1e-3f;
      o4.y = tot[mi][ni][1] * 1e-3f;
      o4.z = tot[mi][ni][2] * 1e-3f;
      o4.w = tot[mi][ni][3] * 1e-3f;
      *(float4*)(out + ((size_t)(b * NO + o)) * NPIX + p) = o4;
    }
}

extern "C" void kernel_launch(void* const* d_in, const int* in_sizes, int n_in,
                              void* d_out, int out_size, void* d_ws, size_t ws_size,
                              hipStream_t stream) {
  const float* x = (const float*)d_in[0];
  const float* w = (const float*)d_in[1];
  float* out = (float*)d_out;

  float* pmax = (float*)d_ws;                                // 1088 slots
  u16* qa = (u16*)((char*)d_ws + 8192);                      // padded acts: 18,939,904 B
  u16* wq = (u16*)((char*)d_ws + 8192 + 18939904 + 8192);    // weights: 256*2592*2 B
  float* lossp = out + (out_size - 1);

  void* args[] = { (void*)&x, (void*)&w, (void*)&pmax, (void*)&qa, (void*)&wq, (void*)&lossp };
  hipLaunchCooperativeKernel((const void*)coop_prep, dim3(1024), dim3(256), args, 0, stream);
  gemm_adc<<<dim3(256, 4), 128, 0, stream>>>(qa, wq, pmax, out);
}

// Round 10
// 158.375 us; speedup vs baseline: 1.8787x; 1.8787x over previous
//
#include <hip/hip_runtime.h>
#include <stdint.h>

typedef unsigned short u16;
typedef __attribute__((ext_vector_type(8))) short short8;
typedef __attribute__((ext_vector_type(4))) float floatx4;

#define NB 32
#define NC 256
#define NH 32
#define NW 32
#define NO 256
#define NPIX (NH*NW)     // 1024
#define KPIX 9
#define NG 9             // subarrays (groups)
#define RUN 32           // padded run length (per kernel-tap within group)
#define GK (NG*RUN)      // 288 k-slots per group
#define KTOT (NG*GK)     // 2592 k-slots
#define PADH 34
#define PADSP (PADH*PADH)       // 1156
#define QA_BSTRIDE (PADSP*NC)   // 295936 elems per batch

#define AS1 __attribute__((address_space(1)))
#define AS3 __attribute__((address_space(3)))

// ---------------- fused: per-block absmax slots + zero qa halo borders ----------------
// blocks [0,1024): x-max -> pmax[bid] ; [1024,1088): w-max ; [1088,1376): border zero
__global__ void fused_pre(const float4* __restrict__ x4, int nx4,
                          const float4* __restrict__ w4, int nw4,
                          float* __restrict__ pmax, u16* __restrict__ qa) {
  int bid = blockIdx.x;
  if (bid >= 1088) {
    int zb = bid - 1088;              // 9 blocks per batch
    int b = zb / 9;
    int rem = (zb % 9) * 256 + threadIdx.x;   // need <2112 (132 px * 16 ch-groups)
    if (rem >= 2112) return;
    int pb = rem >> 4, c16 = rem & 15;
    int y, x;
    if (pb < 68) { y = (pb >= 34) ? 33 : 0; x = pb % 34; }
    else { int q = pb - 68; y = 1 + (q >> 1); x = (q & 1) ? 33 : 0; }
    uint4 z; z.x = z.y = z.z = z.w = 0u;
    *(uint4*)(qa + ((size_t)(b * PADH + y) * PADH + x) * NC + c16 * 16) = z;
    return;
  }
  const float4* p; int n4; int nb, b0;
  if (bid < 1024) { p = x4; n4 = nx4; nb = 1024; b0 = bid; }
  else            { p = w4; n4 = nw4; nb = 64;   b0 = bid - 1024; }
  float m = 0.f;
  for (int i = b0 * blockDim.x + threadIdx.x; i < n4; i += nb * blockDim.x) {
    float4 v = p[i];
    m = fmaxf(m, fmaxf(fmaxf(fabsf(v.x), fabsf(v.y)), fmaxf(fabsf(v.z), fabsf(v.w))));
  }
#pragma unroll
  for (int off = 32; off > 0; off >>= 1)
    m = fmaxf(m, __shfl_down(m, off, 64));
  __shared__ float sm[4];
  int lane = threadIdx.x & 63, wv = threadIdx.x >> 6;
  if (lane == 0) sm[wv] = m;
  __syncthreads();
  if (threadIdx.x == 0)
    pmax[bid] = fmaxf(fmaxf(sm[0], sm[1]), fmaxf(sm[2], sm[3]));
}

// helper: reduce the 1024 x-slots and 64 w-slots
__device__ inline void reduce_pmax(const float* pmax, int tid, int nthreads,
                                   float* sred, float& mx_out, float& mw_out) {
  const float4* pf4 = (const float4*)pmax;
  float mx = 0.f, mw = 0.f;
  for (int t = tid; t < 256; t += nthreads) {
    float4 v = pf4[t];
    mx = fmaxf(mx, fmaxf(fmaxf(v.x, v.y), fmaxf(v.z, v.w)));
  }
  if (tid < 16) {
    float4 v = pf4[256 + tid];
    mw = fmaxf(fmaxf(v.x, v.y), fmaxf(v.z, v.w));
  }
#pragma unroll
  for (int off = 32; off > 0; off >>= 1) {
    mx = fmaxf(mx, __shfl_down(mx, off, 64));
    mw = fmaxf(mw, __shfl_down(mw, off, 64));
  }
  int lane = tid & 63, wv = tid >> 6, nw = nthreads >> 6;
  if (lane == 0) { sred[wv] = mx; sred[8 + wv] = mw; }
  __syncthreads();
  mx = sred[0]; mw = sred[8];
  for (int i = 1; i < nw; i++) { mx = fmaxf(mx, sred[i]); mw = fmaxf(mw, sred[8 + i]); }
  mx_out = mx; mw_out = mw;
}

// ---------------- fused quantization: acts (blocks <1024, vectorized) + weights ----------------
// act: one block per (b,y): 256c x 32x tile. float4 loads, LDS transpose, uint4 stores.
// f64 math EXACTLY as all passing rounds: rint((double)v * (255/s)).
__global__ void fused_quant(const float* __restrict__ x, const float* __restrict__ w,
                            const float* __restrict__ pmax,
                            u16* __restrict__ qa, u16* __restrict__ wq,
                            float* __restrict__ lossp) {
  __shared__ float sred[16];
  float mx, mw;
  reduce_pmax(pmax, threadIdx.x, 256, sred, mx, mw);
  int bid = blockIdx.x, tid = threadIdx.x;
  if (bid < 1024) {
    __shared__ u16 ts[32][264];        // [x][c], row stride 264 (16B-aligned rows)
    double s = (double)mx + 1e-12;
    double inv = 255.0 / s;
    int b = bid >> 5, y = bid & 31;
    const float4* x4 = (const float4*)x;
    int xc = tid & 7, crow = tid >> 3;
#pragma unroll
    for (int it = 0; it < 8; it++) {
      int c = crow + 32 * it;
      float4 v = x4[((size_t)(b * NC + c) * NH + y) * 8 + xc];
      float q0 = (float)rint((double)v.x * inv);
      float q1 = (float)rint((double)v.y * inv);
      float q2 = (float)rint((double)v.z * inv);
      float q3 = (float)rint((double)v.w * inv);
      ts[xc * 4 + 0][c] = (u16)(__float_as_uint(q0) >> 16);
      ts[xc * 4 + 1][c] = (u16)(__float_as_uint(q1) >> 16);
      ts[xc * 4 + 2][c] = (u16)(__float_as_uint(q2) >> 16);
      ts[xc * 4 + 3][c] = (u16)(__float_as_uint(q3) >> 16);
    }
    __syncthreads();
    int xx = tid >> 3, qwl = tid & 7;
    u16* orow = qa + ((size_t)(b * PADH + y + 1) * PADH + (xx + 1)) * NC;
#pragma unroll
    for (int it = 0; it < 4; it++) {
      int qw = qwl + 8 * it;
      *(uint4*)(orow + qw * 8) = *(const uint4*)&ts[xx][qw * 8];
    }
    return;
  }
  // ---- weights: 2592 blocks cover NO*KTOT = 663552 slots exactly ----
  double s = (double)mw + 1e-12;
  double inv = 15.0 / s;
  int idx = (bid - 1024) * 256 + tid;
  if (idx == 0) *lossp = 0.0f;                  // a_loss output
  int o = idx / KTOT, kk = idx % KTOT;
  int g = kk / GK, rem = kk % GK;
  int r = rem / RUN, j = rem % RUN;
  int clo = (256 * g - r + 8) / 9;
  int chi = (256 * (g + 1) - r + 8) / 9; if (chi > NC) chi = NC;
  int cst = clo & ~3;
  int c = cst + j;
  float val = 0.f;
  if (c >= clo && c < chi) {
    float wv = w[((size_t)o * NC + c) * KPIX + r];
    val = (float)rint((double)wv * inv);
  }
  wq[idx] = (u16)(__float_as_uint(val) >> 16);
}

// ---------------- fused GEMM + per-group ADC ----------------
// 128x128 block tile, 256 threads (4 waves x 64x64), grid (256,2)=512 blocks = 2/CU.
// Staged bytes 680 MB (vs R6's 995) at the ~12.3 TB/s per-CU fabric ceiling, with
// 2 blocks/CU for latency overlap (R8's failure was 1/CU). 96-K (3-run) chunks,
// direct-to-LDS 16B async staging, source-side bank swizzle (conflict-free, R4).
__global__ __launch_bounds__(256, 2) void gemm_adc(const u16* __restrict__ qa,
                                                   const u16* __restrict__ wq,
                                                   const float* __restrict__ pmax,
                                                   float* __restrict__ out) {
  __shared__ u16 lA[3 * 128 * RUN];   // 24 KB
  __shared__ u16 lB[3 * 128 * RUN];   // 24 KB
  __shared__ float sred[16];
  const int tid = threadIdx.x;
  float mx, mw;
  reduce_pmax(pmax, tid, 256, sred, mx, mw);

  const int mblk = blockIdx.x, nblk = blockIdx.y;
  const int b = mblk >> 3;
  const int p0 = (mblk & 7) * 128;        // pixel base (4 image rows of 32)
  const int n0 = nblk * 128;
  const int lane = tid & 63, wv = tid >> 6;
  const int wm = (wv & 1) * 64, wn = (wv >> 1) * 64;
  const int fm = lane & 15, fq = lane >> 4;
  const int swz = (fq + ((fm >> 1) & 3)) & 3;

  double sa = (double)mx + 1e-12;
  double sw = (double)mw + 1e-12;
  double Sstep = sa * sw * 0.999 / 459.0;   // I/step = intsum * Sstep

  // staging: slot s = tid + 256*i (i=0..5): run = i>>1, row = (tid>>2) + 64*(i&1), j' = tid&3
  // global k-word jsrc = (j' - (row>>1)) & 3 = ((tid&3) - ((tid>>3)&3)) & 3  (64-row step ok: 32=0 mod 4)
  const int r0 = tid >> 2;
  const int jsrc = ((tid & 3) - ((tid >> 3) & 3)) & 3;
  const u16* AbH[2]; const u16* BbH[2];
#pragma unroll
  for (int h = 0; h < 2; h++) {
    int row = r0 + 64 * h;
    int p = p0 + row;
    AbH[h] = qa + (size_t)b * QA_BSTRIDE
             + (((p >> 5) + 1) * PADH + ((p & 31) + 1)) * NC + jsrc * 8;
    BbH[h] = wq + (size_t)(n0 + row) * KTOT + jsrc * 8;
  }

  floatx4 acc[4][4];
  float tot[4][4][4];
#pragma unroll
  for (int mi = 0; mi < 4; mi++)
#pragma unroll
    for (int ni = 0; ni < 4; ni++)
#pragma unroll
      for (int rr = 0; rr < 4; rr++) { acc[mi][ni][rr] = 0.f; tot[mi][ni][rr] = 0.f; }

#pragma unroll 1
  for (int g = 0; g < NG; g++) {
#pragma unroll 1
    for (int rc = 0; rc < 3; rc++) {
      int offA[3], kb[3];
#pragma unroll
      for (int ri = 0; ri < 3; ri++) {
        int r = rc * 3 + ri;
        int cst = ((256 * g - r + 8) / 9) & ~3;
        offA[ri] = ((rc - 1) * PADH + (ri - 1)) * NC + cst;  // (dy*34+dx)*256 + cst
        kb[ri] = g * GK + r * RUN;
      }
      // A: 6 async 16B loads (3 runs x 2 row-halves of 64)
#pragma unroll
      for (int i = 0; i < 6; i++)
        __builtin_amdgcn_global_load_lds(
            (const AS1 void*)(AbH[i & 1] + offA[i >> 1]),
            (AS3 void*)&lA[(tid + 256 * i) * 8], 16, 0, 0);
      // B: 6 async 16B loads
#pragma unroll
      for (int i = 0; i < 6; i++)
        __builtin_amdgcn_global_load_lds(
            (const AS1 void*)(BbH[i & 1] + kb[i >> 1]),
            (AS3 void*)&lB[(tid + 256 * i) * 8], 16, 0, 0);
      __syncthreads();
      // ---- 3 runs x 16 MFMA per wave ----
#pragma unroll
      for (int ri = 0; ri < 3; ri++) {
        short8 afr[4], bfr[4];
#pragma unroll
        for (int mi = 0; mi < 4; mi++)
          afr[mi] = *(const short8*)&lA[ri * 4096 + (wm + mi * 16 + fm) * RUN + swz * 8];
#pragma unroll
        for (int ni = 0; ni < 4; ni++)
          bfr[ni] = *(const short8*)&lB[ri * 4096 + (wn + ni * 16 + fm) * RUN + swz * 8];
#pragma unroll
        for (int mi = 0; mi < 4; mi++)
#pragma unroll
          for (int ni = 0; ni < 4; ni++)
            acc[mi][ni] = __builtin_amdgcn_mfma_f32_16x16x32_bf16(afr[mi], bfr[ni], acc[mi][ni], 0, 0, 0);
      }
      __syncthreads();
    }
    // ---- per-group ADC fold (f64 mul+rint EXACTLY as the passing kernels) ----
#pragma unroll
    for (int mi = 0; mi < 4; mi++)
#pragma unroll
      for (int ni = 0; ni < 4; ni++)
#pragma unroll
        for (int rr = 0; rr < 4; rr++) {
          double d = (double)acc[mi][ni][rr] * Sstep;
          float tf = (float)rint(d);
          tf = fminf(fmaxf(tf, -128.f), 127.f);
          tot[mi][ni][rr] += tf;
          acc[mi][ni][rr] = 0.f;
        }
  }
  // ---- epilogue ----
#pragma unroll
  for (int mi = 0; mi < 4; mi++)
#pragma unroll
    for (int ni = 0; ni < 4; ni++) {
      int o = n0 + wn + ni * 16 + fm;
      int p = p0 + wm + mi * 16 + fq * 4;
      float4 o4;
      o4.x = tot[mi][ni][0] * 1e-3f;
      o4.y = tot[mi][ni][1] * 1e-3f;
      o4.z = tot[mi][ni][2] * 1e-3f;
      o4.w = tot[mi][ni][3] * 1e-3f;
      *(float4*)(out + ((size_t)(b * NO + o)) * NPIX + p) = o4;
    }
}

extern "C" void kernel_launch(void* const* d_in, const int* in_sizes, int n_in,
                              void* d_out, int out_size, void* d_ws, size_t ws_size,
                              hipStream_t stream) {
  const float* x = (const float*)d_in[0];
  const float* w = (const float*)d_in[1];
  float* out = (float*)d_out;

  float* pmax = (float*)d_ws;                                // 1088 slots
  u16* qa = (u16*)((char*)d_ws + 8192);                      // padded acts: 18,939,904 B
  u16* wq = (u16*)((char*)d_ws + 8192 + 18939904 + 8192);    // weights: 256*2592*2 B

  fused_pre<<<1376, 256, 0, stream>>>((const float4*)x, (NB * NC * NH * NW) / 4,
                                      (const float4*)w, (NO * NC * KPIX) / 4,
                                      pmax, qa);
  fused_quant<<<1024 + 2592, 256, 0, stream>>>(x, w, pmax, qa, wq, out + (out_size - 1));
  gemm_adc<<<dim3(256, 2), 256, 0, stream>>>(qa, wq, pmax, out);
}